// Round 6
// baseline (511.002 us; speedup 1.0000x reference)
//
#include <hip/hip_runtime.h>
#include <math.h>

#define N_TOK 32768
#define IN_DIM 1024
#define HID 256
#define NE 64
#define MT 8        // tokens per wave
#define KU 4        // k per half-chunk (ping-pong)
#define TB 32       // tokens per block
#define KHALF 512   // K per wave (intra-block split-K x2)
#define PH 260      // H LDS pitch (floats), %4==0 for float4, %32==4 -> no gemm2 conflicts

// d_ws: w1t [1024][256] at 0 (262144 floats); w2t [256][64] next (16384).

// ---------------------------------------------------------------------------
// One-time transposes: w1[256][1024]->w1t[1024][256]; w2[64][256]->w2t[256][64]
// ---------------------------------------------------------------------------
__global__ void prep_transpose(const float* __restrict__ w1, const float* __restrict__ w2,
                               float* __restrict__ w1t, float* __restrict__ w2t)
{
    __shared__ float t[32][33];
    const int b = blockIdx.x;
    const float* src; float* dst; int R, C, bx, by;
    if (b < 256) { src = w1; dst = w1t; R = HID; C = IN_DIM; bx = (b & 31) * 32; by = (b >> 5) * 32; }
    else { int bb = b - 256; src = w2; dst = w2t; R = NE; C = HID; bx = (bb & 7) * 32; by = (bb >> 3) * 32; }
    const int lx = threadIdx.x & 31, ly = threadIdx.x >> 5;
    #pragma unroll
    for (int j = 0; j < 4; ++j)
        t[ly + 8 * j][lx] = src[(size_t)(by + ly + 8 * j) * C + bx + lx];
    __syncthreads();
    #pragma unroll
    for (int j = 0; j < 4; ++j)
        dst[(size_t)(bx + ly + 8 * j) * R + by + lx] = t[lx][ly + 8 * j];
}

// ---------------------------------------------------------------------------
// Fused gating: H=relu(X@W1T+b1) [split-K x2, two-phase LDS reduce] ->
// logits=H@W2T+b2 -> shuffle-butterfly top-2 -> softmax.
// 512 thr = 8 waves; waves 0-3: K[0,512), waves 4-7: K[512,1024).
// X wave-uniform -> s_load; W1T k-major -> coalesced dwordx4.
// LDS = single 33.3 KB H slab => 4 blocks/CU = 32 waves/CU (TLP is the
// latency-hiding mechanism; compiler sinks W prefetch regardless).
// ---------------------------------------------------------------------------
__global__ __launch_bounds__(512, 8)
void gating_fused(const float* __restrict__ x, const float* __restrict__ w1t,
                  const float* __restrict__ b1, const float* __restrict__ w2t,
                  const float* __restrict__ b2, float* __restrict__ out)
{
    __shared__ float Hs[TB * PH];   // 33280 B

    const int tid  = threadIdx.x;
    const int lane = tid & 63;
    const int wave = __builtin_amdgcn_readfirstlane(tid >> 6);  // 0..7 uniform
    const int half = wave >> 2;
    const int wv4  = wave & 3;
    const int tloc = wv4 * MT;
    const int tb   = blockIdx.x * TB + tloc;
    const int kbase = half * KHALF;

    const float* xb = x + (size_t)tb * IN_DIM + kbase;          // uniform -> s_load
    const float* wb = w1t + (size_t)kbase * HID + lane * 4;

    float acc[MT][4];
    #pragma unroll
    for (int i = 0; i < MT; ++i)
        #pragma unroll
        for (int j = 0; j < 4; ++j) acc[i][j] = 0.f;

    float4 xA[MT], xB[MT], wA[KU], wB[KU];
    #pragma unroll
    for (int i = 0; i < MT; ++i) xA[i] = *(const float4*)(xb + i * IN_DIM);
    #pragma unroll
    for (int u = 0; u < KU; ++u) wA[u] = *(const float4*)(wb + (size_t)u * HID);

    for (int k0 = 0; k0 < KHALF; k0 += 2 * KU) {
        const int kb = k0 + KU;
        #pragma unroll
        for (int i = 0; i < MT; ++i) xB[i] = *(const float4*)(xb + i * IN_DIM + kb);
        #pragma unroll
        for (int u = 0; u < KU; ++u) wB[u] = *(const float4*)(wb + (size_t)(kb + u) * HID);

        #pragma unroll
        for (int u = 0; u < KU; ++u)
            #pragma unroll
            for (int i = 0; i < MT; ++i) {
                const float xs = ((const float*)&xA[i])[u];
                acc[i][0] = fmaf(xs, wA[u].x, acc[i][0]);
                acc[i][1] = fmaf(xs, wA[u].y, acc[i][1]);
                acc[i][2] = fmaf(xs, wA[u].z, acc[i][2]);
                acc[i][3] = fmaf(xs, wA[u].w, acc[i][3]);
            }

        int ka = k0 + 2 * KU; ka = (ka < KHALF) ? ka : 0;       // last trip: dummy
        #pragma unroll
        for (int i = 0; i < MT; ++i) xA[i] = *(const float4*)(xb + i * IN_DIM + ka);
        #pragma unroll
        for (int u = 0; u < KU; ++u) wA[u] = *(const float4*)(wb + (size_t)(ka + u) * HID);

        #pragma unroll
        for (int u = 0; u < KU; ++u)
            #pragma unroll
            for (int i = 0; i < MT; ++i) {
                const float xs = ((const float*)&xB[i])[u];
                acc[i][0] = fmaf(xs, wB[u].x, acc[i][0]);
                acc[i][1] = fmaf(xs, wB[u].y, acc[i][1]);
                acc[i][2] = fmaf(xs, wB[u].z, acc[i][2]);
                acc[i][3] = fmaf(xs, wB[u].w, acc[i][3]);
            }
    }

    // split-K reduction, two-phase, single slab
    if (half == 0) {
        #pragma unroll
        for (int i = 0; i < MT; ++i)
            *(float4*)(Hs + (tloc + i) * PH + 4 * lane) = *(float4*)&acc[i][0];
    }
    __syncthreads();
    if (half == 1) {
        const float4 bv = *(const float4*)(b1 + 4 * lane);
        #pragma unroll
        for (int i = 0; i < MT; ++i) {
            float* p = Hs + (tloc + i) * PH + 4 * lane;
            float4 v = *(float4*)p;
            v.x = fmaxf(v.x + acc[i][0] + bv.x, 0.f);
            v.y = fmaxf(v.y + acc[i][1] + bv.y, 0.f);
            v.z = fmaxf(v.z + acc[i][2] + bv.z, 0.f);
            v.w = fmaxf(v.w + acc[i][3] + bv.w, 0.f);
            *(float4*)p = v;
        }
    }
    __syncthreads();

    // gemm2: thread -> (token t = tid>>4, experts 4*eg..4*eg+3, eg = tid&15)
    const int t  = tid >> 4;
    const int eg = tid & 15;
    float a2[4] = {0.f, 0.f, 0.f, 0.f};
    const float* wq = w2t + 4 * eg;
    #pragma unroll 8
    for (int k = 0; k < HID; ++k) {
        const float hv = Hs[t * PH + k];                   // 4 addr/wave, broadcast
        const float4 w4 = *(const float4*)(wq + (size_t)k * NE);   // L1-hot
        a2[0] = fmaf(hv, w4.x, a2[0]);
        a2[1] = fmaf(hv, w4.y, a2[1]);
        a2[2] = fmaf(hv, w4.z, a2[2]);
        a2[3] = fmaf(hv, w4.w, a2[3]);
    }
    const float4 bq = *(const float4*)(b2 + 4 * eg);
    const float v0 = a2[0] + bq.x, v1 = a2[1] + bq.y;
    const float v2 = a2[2] + bq.z, v3 = a2[3] + bq.w;

    // local top-2 of 4 (ascending index, strict > => lower index wins ties)
    float m1 = v0, m2; int i1 = 4 * eg, i2;
    if (v1 > m1) { m2 = m1; i2 = i1; m1 = v1; i1 = 4 * eg + 1; }
    else         { m2 = v1; i2 = 4 * eg + 1; }
    if (v2 > m1)      { m2 = m1; i2 = i1; m1 = v2; i1 = 4 * eg + 2; }
    else if (v2 > m2) { m2 = v2; i2 = 4 * eg + 2; }
    if (v3 > m1)      { m2 = m1; i2 = i1; m1 = v3; i1 = 4 * eg + 3; }
    else if (v3 > m2) { m2 = v3; i2 = 4 * eg + 3; }

    // butterfly merge across the token's 16 lanes (masks 1,2,4,8).
    // order: (value, lower index) — matches jax.lax.top_k tie-breaking.
    #pragma unroll
    for (int m = 1; m < 16; m <<= 1) {
        const float o1  = __shfl_xor(m1, m);
        const int   oi1 = __shfl_xor(i1, m);
        const float o2  = __shfl_xor(m2, m);
        const int   oi2 = __shfl_xor(i2, m);
        const bool bTop = (o1 > m1) || (o1 == m1 && oi1 < i1);
        if (bTop) {
            const bool s = (m1 > o2) || (m1 == o2 && i1 < oi2);
            m2 = s ? m1 : o2;  i2 = s ? i1 : oi2;
            m1 = o1;           i1 = oi1;
        } else {
            const bool s = (o1 > m2) || (o1 == m2 && oi1 < i2);
            if (s) { m2 = o1; i2 = oi1; }
        }
    }

    if (eg == 0) {
        const float e2  = expf(m2 - m1);        // <= 1
        const float inv = 1.f / (1.f + e2);
        const int gt = blockIdx.x * TB + t;
        out[(size_t)gt * 2 + 0] = (float)i1;
        out[(size_t)gt * 2 + 1] = (float)i2;
        out[(size_t)2 * N_TOK + (size_t)gt * 2 + 0] = inv;
        out[(size_t)2 * N_TOK + (size_t)gt * 2 + 1] = e2 * inv;
    }
}

extern "C" void kernel_launch(void* const* d_in, const int* in_sizes, int n_in,
                              void* d_out, int out_size, void* d_ws, size_t ws_size,
                              hipStream_t stream) {
    const float* x  = (const float*)d_in[0];
    const float* w1 = (const float*)d_in[1];
    const float* b1 = (const float*)d_in[2];
    const float* w2 = (const float*)d_in[3];
    const float* b2 = (const float*)d_in[4];
    float* out = (float*)d_out;

    float* w1t = (float*)d_ws;                 // 262144 floats
    float* w2t = w1t + (size_t)IN_DIM * HID;   // 16384 floats

    prep_transpose<<<272, 256, 0, stream>>>(w1, w2, w1t, w2t);
    gating_fused<<<N_TOK / TB, 512, 0, stream>>>(x, w1t, b1, w2t, b2, out);
}